// Round 9
// baseline (281.444 us; speedup 1.0000x reference)
//
#include <hip/hip_runtime.h>
#include <stdint.h>

// GraphConvLayer: 3x { x = X@W^T + b; x = Ahat @ x; x *= mask; x = gelu(x) }
// B=32, N=1024, D=256. Split-bf16 (hi/lo) linear; single-term aggregate.
// R9: k_agg restructured — Y chunk-resident in LDS (64KB chunks, dbuf 128KB,
//     staged via plain global->reg->ds_write = the fast path), A reg-direct
//     per-wave (zero dup, zero LDS, zero GLD). 8 barriers total (vs 32).
//     8 waves = 8 M-slices of 16 rows; wave tile 16x256, acc[16].
// Tiled layouts (bf16, 16B-aligned):
//   An : [b][mb=node/128][kt=k/32][row 128][32]   tile stride 4096 elems
//   Yt : [b][kt=node/32][feat 256][32]            tile stride 8192 elems

typedef __attribute__((ext_vector_type(8))) short short8;   // 8 bf16 (4 VGPRs)
typedef __attribute__((ext_vector_type(4))) float f32x4;    // MFMA acc

__device__ __forceinline__ uint16_t f2bf(float f) {
  uint32_t u = __float_as_uint(f);
  u += 0x7FFF + ((u >> 16) & 1);          // RNE
  return (uint16_t)(u >> 16);
}
__device__ __forceinline__ float bf2f(uint16_t h) {
  return __uint_as_float(((uint32_t)h) << 16);
}
__device__ __forceinline__ float gelu_exact(float v) {
  return 0.5f * v * (1.0f + erff(v * 0.70710678118654752f));
}
__device__ __forceinline__ f32x4 mfma16(short8 a, short8 b, f32x4 c) {
  return __builtin_amdgcn_mfma_f32_16x16x32_bf16(a, b, c, 0, 0, 0);
}

#define GLD16(gsrc, ldst) __builtin_amdgcn_global_load_lds(                    \
    (const __attribute__((address_space(1))) void*)(gsrc),                     \
    (__attribute__((address_space(3))) void*)(ldst), 16, 0, 0)

// ---------------- split f32 -> bf16 hi/lo ----------------
__global__ void k_split(const float* __restrict__ src, uint16_t* __restrict__ h,
                        uint16_t* __restrict__ l, int n4) {
  int i = blockIdx.x * blockDim.x + threadIdx.x;
  if (i >= n4) return;
  const float4 v = ((const float4*)src)[i];
  float vv[4] = {v.x, v.y, v.z, v.w};
  ushort4 hh, ll;
  uint16_t* hp = (uint16_t*)&hh;
  uint16_t* lp = (uint16_t*)&ll;
#pragma unroll
  for (int e = 0; e < 4; ++e) {
    uint16_t hb = f2bf(vv[e]);
    hp[e] = hb;
    lp[e] = f2bf(vv[e] - bf2f(hb));
  }
  ((ushort4*)h)[i] = hh;
  ((ushort4*)l)[i] = ll;
}

// ---------------- row-normalize adj -> bf16, TILED store ----------------
__global__ void k_norm_adj(const float* __restrict__ adj, uint16_t* __restrict__ An) {
  const int r = blockIdx.x;       // 0..32767 = b*1024 + node
  const int t = threadIdx.x;      // 0..255, handles k = t*4 .. t*4+3
  const float* row = adj + (size_t)r * 1024;
  const float4 v = *(const float4*)(row + t * 4);
  float s = v.x + v.y + v.z + v.w;
#pragma unroll
  for (int off = 32; off; off >>= 1) s += __shfl_down(s, off);
  __shared__ float ws[4];
  if ((t & 63) == 0) ws[t >> 6] = s;
  __syncthreads();
  const float deg = ws[0] + ws[1] + ws[2] + ws[3];
  const float dinv = (deg != 0.f) ? 1.f / deg : 0.f;
  ushort4 o;
  uint16_t* op = (uint16_t*)&o;
  float vv[4] = {v.x, v.y, v.z, v.w};
#pragma unroll
  for (int e = 0; e < 4; ++e) op[e] = f2bf(vv[e] * dinv);
  // tiled: [b][mb][kt][row 128][32]
  const int b = r >> 10, node = r & 1023;
  const int mb = node >> 7, rr = node & 127;
  const int kt = t >> 3, ko = (t * 4) & 31;
  const size_t oo = (size_t)(b * 8 + mb) * 131072 + kt * 4096 + rr * 32 + ko;
  *(ushort4*)(An + oo) = o;
}

// ---------------- linear: Yt = (X @ W^T + b), 3-term, TILED hi-only store ----------------
__global__ __launch_bounds__(256) void k_linear(
    const uint16_t* __restrict__ Xh, const uint16_t* __restrict__ Xl,
    const uint16_t* __restrict__ Wh, const uint16_t* __restrict__ Wl,
    const float* __restrict__ bias,
    uint16_t* __restrict__ Yth) {
  __shared__ __align__(16) uint8_t smem[32768];  // Ah|Al|Wh|Wl tiles, 8KB each
  const int tid = threadIdx.x;
  const int lane = tid & 63;
  const int wave = tid >> 6;
  const int wr = wave >> 1, wc = wave & 1;
  const int m0 = blockIdx.x * 128;   // global row (b*1024+node)
  const int n0 = blockIdx.y * 128;   // out-feature
  const int lm = lane & 15, g = lane >> 4;
  const int srow = lane >> 2;
  const int skof = (lane & 3) * 8;

  f32x4 acc[4][4] = {};

  for (int kt = 0; kt < 8; ++kt) {
    const int k0 = kt * 32;
    __syncthreads();
#pragma unroll
    for (int j = 0; j < 8; ++j) {
      const int c = j * 4 + wave;    // 0..31
      const int sub = c & 7, which = c >> 3;
      const int row = sub * 16 + srow;
      const uint16_t* src;
      if (which == 0)      src = Xh + (size_t)(m0 + row) * 256 + k0 + skof;
      else if (which == 1) src = Xl + (size_t)(m0 + row) * 256 + k0 + skof;
      else if (which == 2) src = Wh + (size_t)(n0 + row) * 256 + k0 + skof;
      else                 src = Wl + (size_t)(n0 + row) * 256 + k0 + skof;
      GLD16(src, smem + c * 1024);
    }
    asm volatile("s_waitcnt vmcnt(0)" ::: "memory");
    __syncthreads();

    const uint8_t* Ahs = smem;
    const uint8_t* Als = smem + 8192;
    const uint8_t* Bhs = smem + 16384;
    const uint8_t* Bls = smem + 24576;
    short8 ah[4], al[4], bh[4], bl[4];
#pragma unroll
    for (int f = 0; f < 4; ++f) {
      ah[f] = *(const short8*)(Ahs + (wr * 64 + f * 16 + lm) * 64 + g * 16);
      al[f] = *(const short8*)(Als + (wr * 64 + f * 16 + lm) * 64 + g * 16);
      bh[f] = *(const short8*)(Bhs + (wc * 64 + f * 16 + lm) * 64 + g * 16);
      bl[f] = *(const short8*)(Bls + (wc * 64 + f * 16 + lm) * 64 + g * 16);
    }
#pragma unroll
    for (int fm = 0; fm < 4; ++fm)
#pragma unroll
      for (int fn = 0; fn < 4; ++fn) {
        acc[fm][fn] = mfma16(ah[fm], bh[fn], acc[fm][fn]);
        acc[fm][fn] = mfma16(ah[fm], bl[fn], acc[fm][fn]);
        acc[fm][fn] = mfma16(al[fm], bh[fn], acc[fm][fn]);
      }
  }

  // epilogue: +bias, store hi-only TILED [b][kt][feat][32]
#pragma unroll
  for (int fn = 0; fn < 4; ++fn) {
    const int n = n0 + wc * 64 + fn * 16 + lm;
    const float bv = bias[n];
#pragma unroll
    for (int fm = 0; fm < 4; ++fm) {
      const int mg = m0 + wr * 64 + fm * 16 + g * 4;
      const int bb = mg >> 10, node = mg & 1023;
      const int kt = node >> 5, ko = node & 31;
      ushort4 hh;
      uint16_t* hp = (uint16_t*)&hh;
#pragma unroll
      for (int e = 0; e < 4; ++e) hp[e] = f2bf(acc[fm][fn][e] + bv);
      const size_t o = ((size_t)(bb * 32 + kt) * 256 + n) * 32 + ko;
      *(ushort4*)(Yth + o) = hh;
    }
  }
}

// ---------------- aggregate: Z = An[b] @ Yh, mask, gelu ----------------
// Block: 128(M) x 256(N), K=1024. 8 waves, each owns 16 M-rows (wave 16x256).
// Y staged in 64KB chunks (4 K-steps of 32) via plain load -> reg -> ds_write,
// double-buffered (128KB LDS). A read reg-direct per wave (no LDS, no dup).
// 8 super-steps, ONE barrier each.
template <bool LAST>
__global__ __launch_bounds__(512, 1) void k_agg(
    const uint16_t* __restrict__ An,
    const uint16_t* __restrict__ Yth,
    const float* __restrict__ mask,
    uint16_t* __restrict__ Xh, uint16_t* __restrict__ Xl,
    float* __restrict__ out) {
  __shared__ __align__(16) uint8_t smem[131072];   // 2 x 65536 (Y chunk dbuf)
  const int tid = threadIdx.x;
  const int lane = tid & 63;
  const int w = tid >> 6;               // 0..7 = M-slice
  const int id = blockIdx.x;            // 0..255
  const int swz = (id & 7) * 32 + (id >> 3);      // XCD-chunked (bijective)
  const int b = swz >> 3;               // batch
  const int mb = swz & 7;               // node block (of 128)
  const int lm = lane & 15, g = lane >> 4;

  const uint16_t* gA = An  + (size_t)(b * 8 + mb) * 131072;  // [kt][128][32]
  const uint16_t* gH = Yth + (size_t)b * 262144;             // [kt][256][32]
  // A fragment source for k-step kt: rows w*16+lm, k-elems g*8..
  const uint16_t* aSrc = gA + (w * 16 + lm) * 32 + g * 8;
  // Y chunk staging source: 8 x int4 per thread covers 32768 elems (64KB)
  const uint16_t* ySrc = gH + tid * 8;

  f32x4 acc[16] = {};
  int4 y[8];

  // prologue: stage chunk 0 into buf0
#pragma unroll
  for (int j = 0; j < 8; ++j) y[j] = *(const int4*)(ySrc + j * 4096);
#pragma unroll
  for (int j = 0; j < 8; ++j) *(int4*)(smem + j * 8192 + tid * 16) = y[j];

#pragma unroll 1
  for (int c = 0; c < 8; ++c) {
    asm volatile("s_waitcnt lgkmcnt(0)" ::: "memory");
    __builtin_amdgcn_sched_barrier(0);
    __builtin_amdgcn_s_barrier();
    const uint8_t* rbuf = smem + (c & 1) * 65536;
    uint8_t* wbuf = smem + ((c + 1) & 1) * 65536;

    // issue A fragments for this super-step's 4 k-steps (oldest loads)
    short8 af0 = *(const short8*)(aSrc + (size_t)(4 * c + 0) * 4096);
    short8 af1 = *(const short8*)(aSrc + (size_t)(4 * c + 1) * 4096);
    short8 af2 = *(const short8*)(aSrc + (size_t)(4 * c + 2) * 4096);
    short8 af3 = *(const short8*)(aSrc + (size_t)(4 * c + 3) * 4096);
    __builtin_amdgcn_sched_barrier(0);
    // issue next Y chunk loads (newer -> af uses won't drain them)
    if (c < 7) {
#pragma unroll
      for (int j = 0; j < 8; ++j)
        y[j] = *(const int4*)(ySrc + (size_t)(c + 1) * 32768 + j * 4096);
    }
    __builtin_amdgcn_sched_barrier(0);

    // compute 4 k-steps from resident chunk
#pragma unroll
    for (int i = 0; i < 4; ++i) {
      const uint8_t* kb = rbuf + i * 16384;
      const short8 afi = (i == 0) ? af0 : (i == 1) ? af1 : (i == 2) ? af2 : af3;
      __builtin_amdgcn_s_setprio(1);
#pragma unroll
      for (int fn = 0; fn < 16; ++fn) {
        const short8 hf = *(const short8*)(kb + (fn * 16 + lm) * 64 + g * 16);
        acc[fn] = mfma16(afi, hf, acc[fn]);
      }
      __builtin_amdgcn_s_setprio(0);
    }

    // write staged chunk to the other buffer (visible after next barrier)
    if (c < 7) {
      __builtin_amdgcn_sched_barrier(0);
#pragma unroll
      for (int j = 0; j < 8; ++j) *(int4*)(wbuf + j * 8192 + tid * 16) = y[j];
    }
  }

  // epilogue: mask (per out-node), exact gelu, store row-major
  const float* mk_b = mask + b * 1024;
  const int m_base = mb * 128 + w * 16 + g * 4;
  float mk[4];
#pragma unroll
  for (int e = 0; e < 4; ++e) mk[e] = mk_b[m_base + e];
#pragma unroll
  for (int fn = 0; fn < 16; ++fn) {
    const int n = fn * 16 + lm;
#pragma unroll
    for (int e = 0; e < 4; ++e) {
      const float v = gelu_exact(acc[fn][e] * mk[e]);
      const size_t o = ((size_t)(b * 1024 + m_base + e)) * 256 + n;
      if (LAST) {
        out[o] = v;
      } else {
        const uint16_t hb = f2bf(v);
        Xh[o] = hb;
        Xl[o] = f2bf(v - bf2f(hb));
      }
    }
  }
}

extern "C" void kernel_launch(void* const* d_in, const int* in_sizes, int n_in,
                              void* d_out, int out_size, void* d_ws, size_t ws_size,
                              hipStream_t stream) {
  const float* x    = (const float*)d_in[0];
  const float* mask = (const float*)d_in[1];
  const float* adj  = (const float*)d_in[2];
  const float* W[3]  = {(const float*)d_in[3], (const float*)d_in[5], (const float*)d_in[7]};
  const float* bs[3] = {(const float*)d_in[4], (const float*)d_in[6], (const float*)d_in[8]};

  uint8_t* ws = (uint8_t*)d_ws;
  uint16_t* An  = (uint16_t*)(ws);                    // 67108864 B (tiled)
  uint16_t* Xh  = (uint16_t*)(ws + 67108864);         // 16777216
  uint16_t* Xl  = (uint16_t*)(ws + 83886080);         // 16777216
  uint16_t* Yth = (uint16_t*)(ws + 100663296);        // 16777216 (tiled)
  uint16_t* Wh  = (uint16_t*)(ws + 134217728);        // 393216
  uint16_t* Wl  = (uint16_t*)(ws + 134610944);        // 393216

  k_split<<<dim3(8192), 256, 0, stream>>>(x, Xh, Xl, 2097152);
  for (int i = 0; i < 3; ++i)
    k_split<<<dim3(64), 256, 0, stream>>>(W[i], Wh + i * 65536, Wl + i * 65536, 16384);
  k_norm_adj<<<dim3(32768), 256, 0, stream>>>(adj, An);

  for (int l = 0; l < 3; ++l) {
    k_linear<<<dim3(256, 2), 256, 0, stream>>>(Xh, Xl, Wh + l * 65536, Wl + l * 65536,
                                               bs[l], Yth);
    if (l < 2)
      k_agg<false><<<dim3(256), 512, 0, stream>>>(An, Yth, mask, Xh, Xl, nullptr);
    else
      k_agg<true><<<dim3(256), 512, 0, stream>>>(An, Yth, mask, nullptr, nullptr,
                                                 (float*)d_out);
  }
}

// Round 10
// 202.489 us; speedup vs baseline: 1.3899x; 1.3899x over previous
//
#include <hip/hip_runtime.h>
#include <stdint.h>

// GraphConvLayer: 3x { x = X@W^T + b; x = Ahat @ x; x *= mask; x = gelu(x) }
// B=32, N=1024, D=256. Split-bf16 (hi/lo) linear; single-term aggregate.
// R10: k_agg = BM 64, grid 512 -> TWO independent blocks per CU (cross-block
//      latency masking, the property every 1-block/CU design lacked).
//      4 waves (2Mx2N, wave 32x128), 3-slot ring of 20KB (A4K+Y16K) = 60KB,
//      GLD staging 5/wave/step, counted vmcnt(5). Numerics identical to R8.
// Tiled layouts (bf16, 16B-aligned):
//   An : [b][mb=node/128][kt=k/32][row 128][32]   tile stride 4096 elems
//   Yt : [b][kt=node/32][feat 256][32]            tile stride 8192 elems

typedef __attribute__((ext_vector_type(8))) short short8;   // 8 bf16 (4 VGPRs)
typedef __attribute__((ext_vector_type(4))) float f32x4;    // MFMA acc

__device__ __forceinline__ uint16_t f2bf(float f) {
  uint32_t u = __float_as_uint(f);
  u += 0x7FFF + ((u >> 16) & 1);          // RNE
  return (uint16_t)(u >> 16);
}
__device__ __forceinline__ float bf2f(uint16_t h) {
  return __uint_as_float(((uint32_t)h) << 16);
}
__device__ __forceinline__ float gelu_exact(float v) {
  return 0.5f * v * (1.0f + erff(v * 0.70710678118654752f));
}
__device__ __forceinline__ f32x4 mfma16(short8 a, short8 b, f32x4 c) {
  return __builtin_amdgcn_mfma_f32_16x16x32_bf16(a, b, c, 0, 0, 0);
}

#define GLD16(gsrc, ldst) __builtin_amdgcn_global_load_lds(                    \
    (const __attribute__((address_space(1))) void*)(gsrc),                     \
    (__attribute__((address_space(3))) void*)(ldst), 16, 0, 0)

// ---------------- split f32 -> bf16 hi/lo ----------------
__global__ void k_split(const float* __restrict__ src, uint16_t* __restrict__ h,
                        uint16_t* __restrict__ l, int n4) {
  int i = blockIdx.x * blockDim.x + threadIdx.x;
  if (i >= n4) return;
  const float4 v = ((const float4*)src)[i];
  float vv[4] = {v.x, v.y, v.z, v.w};
  ushort4 hh, ll;
  uint16_t* hp = (uint16_t*)&hh;
  uint16_t* lp = (uint16_t*)&ll;
#pragma unroll
  for (int e = 0; e < 4; ++e) {
    uint16_t hb = f2bf(vv[e]);
    hp[e] = hb;
    lp[e] = f2bf(vv[e] - bf2f(hb));
  }
  ((ushort4*)h)[i] = hh;
  ((ushort4*)l)[i] = ll;
}

// ---------------- row-normalize adj -> bf16, TILED store ----------------
__global__ void k_norm_adj(const float* __restrict__ adj, uint16_t* __restrict__ An) {
  const int r = blockIdx.x;       // 0..32767 = b*1024 + node
  const int t = threadIdx.x;      // 0..255, handles k = t*4 .. t*4+3
  const float* row = adj + (size_t)r * 1024;
  const float4 v = *(const float4*)(row + t * 4);
  float s = v.x + v.y + v.z + v.w;
#pragma unroll
  for (int off = 32; off; off >>= 1) s += __shfl_down(s, off);
  __shared__ float ws[4];
  if ((t & 63) == 0) ws[t >> 6] = s;
  __syncthreads();
  const float deg = ws[0] + ws[1] + ws[2] + ws[3];
  const float dinv = (deg != 0.f) ? 1.f / deg : 0.f;
  ushort4 o;
  uint16_t* op = (uint16_t*)&o;
  float vv[4] = {v.x, v.y, v.z, v.w};
#pragma unroll
  for (int e = 0; e < 4; ++e) op[e] = f2bf(vv[e] * dinv);
  // tiled: [b][mb][kt][row 128][32]
  const int b = r >> 10, node = r & 1023;
  const int mb = node >> 7, rr = node & 127;
  const int kt = t >> 3, ko = (t * 4) & 31;
  const size_t oo = (size_t)(b * 8 + mb) * 131072 + kt * 4096 + rr * 32 + ko;
  *(ushort4*)(An + oo) = o;
}

// ---------------- linear: Yt = (X @ W^T + b), 3-term, TILED hi-only store ----------------
__global__ __launch_bounds__(256) void k_linear(
    const uint16_t* __restrict__ Xh, const uint16_t* __restrict__ Xl,
    const uint16_t* __restrict__ Wh, const uint16_t* __restrict__ Wl,
    const float* __restrict__ bias,
    uint16_t* __restrict__ Yth) {
  __shared__ __align__(16) uint8_t smem[32768];  // Ah|Al|Wh|Wl tiles, 8KB each
  const int tid = threadIdx.x;
  const int lane = tid & 63;
  const int wave = tid >> 6;
  const int wr = wave >> 1, wc = wave & 1;
  const int m0 = blockIdx.x * 128;   // global row (b*1024+node)
  const int n0 = blockIdx.y * 128;   // out-feature
  const int lm = lane & 15, g = lane >> 4;
  const int srow = lane >> 2;
  const int skof = (lane & 3) * 8;

  f32x4 acc[4][4] = {};

  for (int kt = 0; kt < 8; ++kt) {
    const int k0 = kt * 32;
    __syncthreads();
#pragma unroll
    for (int j = 0; j < 8; ++j) {
      const int c = j * 4 + wave;    // 0..31
      const int sub = c & 7, which = c >> 3;
      const int row = sub * 16 + srow;
      const uint16_t* src;
      if (which == 0)      src = Xh + (size_t)(m0 + row) * 256 + k0 + skof;
      else if (which == 1) src = Xl + (size_t)(m0 + row) * 256 + k0 + skof;
      else if (which == 2) src = Wh + (size_t)(n0 + row) * 256 + k0 + skof;
      else                 src = Wl + (size_t)(n0 + row) * 256 + k0 + skof;
      GLD16(src, smem + c * 1024);
    }
    asm volatile("s_waitcnt vmcnt(0)" ::: "memory");
    __syncthreads();

    const uint8_t* Ahs = smem;
    const uint8_t* Als = smem + 8192;
    const uint8_t* Bhs = smem + 16384;
    const uint8_t* Bls = smem + 24576;
    short8 ah[4], al[4], bh[4], bl[4];
#pragma unroll
    for (int f = 0; f < 4; ++f) {
      ah[f] = *(const short8*)(Ahs + (wr * 64 + f * 16 + lm) * 64 + g * 16);
      al[f] = *(const short8*)(Als + (wr * 64 + f * 16 + lm) * 64 + g * 16);
      bh[f] = *(const short8*)(Bhs + (wc * 64 + f * 16 + lm) * 64 + g * 16);
      bl[f] = *(const short8*)(Bls + (wc * 64 + f * 16 + lm) * 64 + g * 16);
    }
#pragma unroll
    for (int fm = 0; fm < 4; ++fm)
#pragma unroll
      for (int fn = 0; fn < 4; ++fn) {
        acc[fm][fn] = mfma16(ah[fm], bh[fn], acc[fm][fn]);
        acc[fm][fn] = mfma16(ah[fm], bl[fn], acc[fm][fn]);
        acc[fm][fn] = mfma16(al[fm], bh[fn], acc[fm][fn]);
      }
  }

  // epilogue: +bias, store hi-only TILED [b][kt][feat][32]
#pragma unroll
  for (int fn = 0; fn < 4; ++fn) {
    const int n = n0 + wc * 64 + fn * 16 + lm;
    const float bv = bias[n];
#pragma unroll
    for (int fm = 0; fm < 4; ++fm) {
      const int mg = m0 + wr * 64 + fm * 16 + g * 4;
      const int bb = mg >> 10, node = mg & 1023;
      const int kt = node >> 5, ko = node & 31;
      ushort4 hh;
      uint16_t* hp = (uint16_t*)&hh;
#pragma unroll
      for (int e = 0; e < 4; ++e) hp[e] = f2bf(acc[fm][fn][e] + bv);
      const size_t o = ((size_t)(bb * 32 + kt) * 256 + n) * 32 + ko;
      *(ushort4*)(Yth + o) = hh;
    }
  }
}

// ---------------- aggregate: Z = An[b] @ Yh, mask, gelu ----------------
// BM=64, BN=256, BK=32. Grid 512 (2 blocks/CU). 4 waves (2M x 2N), wave
// tile 32x128 (acc[2][8]). 3-slot LDS ring, slot = [A 4KB | Yh 16KB] = 20KB.
// 5 GLD/wave/step (chunks c = w*5+j; c<4 -> A, else Y). vmcnt(5) counted.
#define STAGE(T, SSL) {                                                        \
    _Pragma("unroll")                                                          \
    for (int j = 0; j < 5; ++j) {                                              \
      const int c = w * 5 + j;                                                 \
      const uint16_t* src = (c < 4)                                            \
          ? aStep + (size_t)(T) * 4096 + c * 512                               \
          : yStep + (size_t)(T) * 8192 + (c - 4) * 512;                        \
      GLD16(src, smem + (SSL) + c * 1024);                                     \
    }                                                                          \
  }

template <bool LAST>
__global__ __launch_bounds__(256, 2) void k_agg(
    const uint16_t* __restrict__ An,
    const uint16_t* __restrict__ Yth,
    const float* __restrict__ mask,
    uint16_t* __restrict__ Xh, uint16_t* __restrict__ Xl,
    float* __restrict__ out) {
  __shared__ __align__(16) uint8_t smem[61440];   // 3 x 20480 ring
  const int tid = threadIdx.x;
  const int lane = tid & 63;
  const int w = tid >> 6;               // 0..3
  const int wm = w >> 1, wn = w & 1;    // 2(M) x 2(N)
  const int id = blockIdx.x;            // 0..511
  const int swz = (id & 7) * 64 + (id >> 3);      // XCD-chunked (bijective)
  const int b = swz >> 4;               // batch
  const int mb2 = swz & 15;             // 64-row block
  const int lm = lane & 15, g = lane >> 4;

  // per-lane staging sources (tiled layouts are GLD-linear)
  const uint16_t* aStep = An + (size_t)(b * 8 + (mb2 >> 1)) * 131072
                             + (mb2 & 1) * 2048 + lane * 8;
  const uint16_t* yStep = Yth + (size_t)b * 262144 + lane * 8;

  // fragment read offsets (byte, slot-local)
  const int aoff = (wm * 32 + lm) * 64 + g * 16;           // + fm*1024
  const int boff = 4096 + (wn * 128 + lm) * 64 + g * 16;   // + fn*1024

  f32x4 acc[2][8] = {};

  // prologue: stage tiles 0,1 into slots 0,1
  STAGE(0, 0);
  STAGE(1, 20480);

  int csl = 0, ssl = 40960;   // compute-slot, stage-slot byte offsets
#pragma unroll 1
  for (int t = 0; t < 32; ++t) {
    if (t < 31) { asm volatile("s_waitcnt vmcnt(5)" ::: "memory"); }
    else        { asm volatile("s_waitcnt vmcnt(0)" ::: "memory"); }
    __builtin_amdgcn_s_barrier();
    __builtin_amdgcn_sched_barrier(0);
    if (t < 30) { STAGE(t + 2, ssl); }
    __builtin_amdgcn_sched_barrier(0);

    const uint8_t* sb = smem + csl;
    const short8 af0 = *(const short8*)(sb + aoff);
    const short8 af1 = *(const short8*)(sb + aoff + 1024);
    __builtin_amdgcn_s_setprio(1);
#pragma unroll
    for (int fn = 0; fn < 8; ++fn) {
      const short8 hf = *(const short8*)(sb + boff + fn * 1024);
      acc[0][fn] = mfma16(af0, hf, acc[0][fn]);
      acc[1][fn] = mfma16(af1, hf, acc[1][fn]);
    }
    __builtin_amdgcn_s_setprio(0);

    csl += 20480; if (csl == 61440) csl = 0;
    ssl += 20480; if (ssl == 61440) ssl = 0;
  }

  // epilogue: mask (per out-node), exact gelu, store row-major
  const float* mk_b = mask + b * 1024;
  const int m0 = mb2 * 64 + wm * 32;
#pragma unroll
  for (int fm = 0; fm < 2; ++fm) {
    const int m = m0 + fm * 16 + g * 4;
    float mk[4];
#pragma unroll
    for (int e = 0; e < 4; ++e) mk[e] = mk_b[m + e];
#pragma unroll
    for (int fn = 0; fn < 8; ++fn) {
      const int n = wn * 128 + fn * 16 + lm;
#pragma unroll
      for (int e = 0; e < 4; ++e) {
        const float v = gelu_exact(acc[fm][fn][e] * mk[e]);
        const size_t o = ((size_t)(b * 1024 + m + e)) * 256 + n;
        if (LAST) {
          out[o] = v;
        } else {
          const uint16_t hb = f2bf(v);
          Xh[o] = hb;
          Xl[o] = f2bf(v - bf2f(hb));
        }
      }
    }
  }
}

extern "C" void kernel_launch(void* const* d_in, const int* in_sizes, int n_in,
                              void* d_out, int out_size, void* d_ws, size_t ws_size,
                              hipStream_t stream) {
  const float* x    = (const float*)d_in[0];
  const float* mask = (const float*)d_in[1];
  const float* adj  = (const float*)d_in[2];
  const float* W[3]  = {(const float*)d_in[3], (const float*)d_in[5], (const float*)d_in[7]};
  const float* bs[3] = {(const float*)d_in[4], (const float*)d_in[6], (const float*)d_in[8]};

  uint8_t* ws = (uint8_t*)d_ws;
  uint16_t* An  = (uint16_t*)(ws);                    // 67108864 B (tiled)
  uint16_t* Xh  = (uint16_t*)(ws + 67108864);         // 16777216
  uint16_t* Xl  = (uint16_t*)(ws + 83886080);         // 16777216
  uint16_t* Yth = (uint16_t*)(ws + 100663296);        // 16777216 (tiled)
  uint16_t* Wh  = (uint16_t*)(ws + 134217728);        // 393216
  uint16_t* Wl  = (uint16_t*)(ws + 134610944);        // 393216

  k_split<<<dim3(8192), 256, 0, stream>>>(x, Xh, Xl, 2097152);
  for (int i = 0; i < 3; ++i)
    k_split<<<dim3(64), 256, 0, stream>>>(W[i], Wh + i * 65536, Wl + i * 65536, 16384);
  k_norm_adj<<<dim3(32768), 256, 0, stream>>>(adj, An);

  for (int l = 0; l < 3; ++l) {
    k_linear<<<dim3(256, 2), 256, 0, stream>>>(Xh, Xl, Wh + l * 65536, Wl + l * 65536,
                                               bs[l], Yth);
    if (l < 2)
      k_agg<false><<<dim3(512), 256, 0, stream>>>(An, Yth, mask, Xh, Xl, nullptr);
    else
      k_agg<true><<<dim3(512), 256, 0, stream>>>(An, Yth, mask, nullptr, nullptr,
                                                 (float*)d_out);
  }
}

// Round 11
// 200.462 us; speedup vs baseline: 1.4040x; 1.0101x over previous
//
#include <hip/hip_runtime.h>
#include <stdint.h>

// GraphConvLayer: 3x { x = X@W^T + b; x = Ahat @ x; x *= mask; x = gelu(x) }
// B=32, N=1024, D=256. Split-bf16 (hi/lo) linear; single-term aggregate.
// R11: k_agg geometry BM=128 x BN=128 (grid 512 = 2 blocks/CU): Y dup stays
//      8x (256MB total ingest, -20% vs R10) while keeping 2 independent
//      barrier domains per CU. 4 waves 2Mx2N, wave tile 64x64 (acc[4][4]),
//      3-slot ring of 16KB (A8K+Yhalf8K) = 48KB, 4 GLD/wave/step, vmcnt(4).
// Tiled layouts (bf16, 16B-aligned):
//   An : [b][mb=node/128][kt=k/32][row 128][32]   tile stride 4096 elems
//   Yt : [b][kt=node/32][feat 256][32]            tile stride 8192 elems

typedef __attribute__((ext_vector_type(8))) short short8;   // 8 bf16 (4 VGPRs)
typedef __attribute__((ext_vector_type(4))) float f32x4;    // MFMA acc

__device__ __forceinline__ uint16_t f2bf(float f) {
  uint32_t u = __float_as_uint(f);
  u += 0x7FFF + ((u >> 16) & 1);          // RNE
  return (uint16_t)(u >> 16);
}
__device__ __forceinline__ float bf2f(uint16_t h) {
  return __uint_as_float(((uint32_t)h) << 16);
}
__device__ __forceinline__ float gelu_exact(float v) {
  return 0.5f * v * (1.0f + erff(v * 0.70710678118654752f));
}
__device__ __forceinline__ f32x4 mfma16(short8 a, short8 b, f32x4 c) {
  return __builtin_amdgcn_mfma_f32_16x16x32_bf16(a, b, c, 0, 0, 0);
}

#define GLD16(gsrc, ldst) __builtin_amdgcn_global_load_lds(                    \
    (const __attribute__((address_space(1))) void*)(gsrc),                     \
    (__attribute__((address_space(3))) void*)(ldst), 16, 0, 0)

// ---------------- split f32 -> bf16 hi/lo ----------------
__global__ void k_split(const float* __restrict__ src, uint16_t* __restrict__ h,
                        uint16_t* __restrict__ l, int n4) {
  int i = blockIdx.x * blockDim.x + threadIdx.x;
  if (i >= n4) return;
  const float4 v = ((const float4*)src)[i];
  float vv[4] = {v.x, v.y, v.z, v.w};
  ushort4 hh, ll;
  uint16_t* hp = (uint16_t*)&hh;
  uint16_t* lp = (uint16_t*)&ll;
#pragma unroll
  for (int e = 0; e < 4; ++e) {
    uint16_t hb = f2bf(vv[e]);
    hp[e] = hb;
    lp[e] = f2bf(vv[e] - bf2f(hb));
  }
  ((ushort4*)h)[i] = hh;
  ((ushort4*)l)[i] = ll;
}

// ---------------- row-normalize adj -> bf16, TILED store ----------------
__global__ void k_norm_adj(const float* __restrict__ adj, uint16_t* __restrict__ An) {
  const int r = blockIdx.x;       // 0..32767 = b*1024 + node
  const int t = threadIdx.x;      // 0..255, handles k = t*4 .. t*4+3
  const float* row = adj + (size_t)r * 1024;
  const float4 v = *(const float4*)(row + t * 4);
  float s = v.x + v.y + v.z + v.w;
#pragma unroll
  for (int off = 32; off; off >>= 1) s += __shfl_down(s, off);
  __shared__ float ws[4];
  if ((t & 63) == 0) ws[t >> 6] = s;
  __syncthreads();
  const float deg = ws[0] + ws[1] + ws[2] + ws[3];
  const float dinv = (deg != 0.f) ? 1.f / deg : 0.f;
  ushort4 o;
  uint16_t* op = (uint16_t*)&o;
  float vv[4] = {v.x, v.y, v.z, v.w};
#pragma unroll
  for (int e = 0; e < 4; ++e) op[e] = f2bf(vv[e] * dinv);
  // tiled: [b][mb][kt][row 128][32]
  const int b = r >> 10, node = r & 1023;
  const int mb = node >> 7, rr = node & 127;
  const int kt = t >> 3, ko = (t * 4) & 31;
  const size_t oo = (size_t)(b * 8 + mb) * 131072 + kt * 4096 + rr * 32 + ko;
  *(ushort4*)(An + oo) = o;
}

// ---------------- linear: Yt = (X @ W^T + b), 3-term, TILED hi-only store ----------------
__global__ __launch_bounds__(256) void k_linear(
    const uint16_t* __restrict__ Xh, const uint16_t* __restrict__ Xl,
    const uint16_t* __restrict__ Wh, const uint16_t* __restrict__ Wl,
    const float* __restrict__ bias,
    uint16_t* __restrict__ Yth) {
  __shared__ __align__(16) uint8_t smem[32768];  // Ah|Al|Wh|Wl tiles, 8KB each
  const int tid = threadIdx.x;
  const int lane = tid & 63;
  const int wave = tid >> 6;
  const int wr = wave >> 1, wc = wave & 1;
  const int m0 = blockIdx.x * 128;   // global row (b*1024+node)
  const int n0 = blockIdx.y * 128;   // out-feature
  const int lm = lane & 15, g = lane >> 4;
  const int srow = lane >> 2;
  const int skof = (lane & 3) * 8;

  f32x4 acc[4][4] = {};

  for (int kt = 0; kt < 8; ++kt) {
    const int k0 = kt * 32;
    __syncthreads();
#pragma unroll
    for (int j = 0; j < 8; ++j) {
      const int c = j * 4 + wave;    // 0..31
      const int sub = c & 7, which = c >> 3;
      const int row = sub * 16 + srow;
      const uint16_t* src;
      if (which == 0)      src = Xh + (size_t)(m0 + row) * 256 + k0 + skof;
      else if (which == 1) src = Xl + (size_t)(m0 + row) * 256 + k0 + skof;
      else if (which == 2) src = Wh + (size_t)(n0 + row) * 256 + k0 + skof;
      else                 src = Wl + (size_t)(n0 + row) * 256 + k0 + skof;
      GLD16(src, smem + c * 1024);
    }
    asm volatile("s_waitcnt vmcnt(0)" ::: "memory");
    __syncthreads();

    const uint8_t* Ahs = smem;
    const uint8_t* Als = smem + 8192;
    const uint8_t* Bhs = smem + 16384;
    const uint8_t* Bls = smem + 24576;
    short8 ah[4], al[4], bh[4], bl[4];
#pragma unroll
    for (int f = 0; f < 4; ++f) {
      ah[f] = *(const short8*)(Ahs + (wr * 64 + f * 16 + lm) * 64 + g * 16);
      al[f] = *(const short8*)(Als + (wr * 64 + f * 16 + lm) * 64 + g * 16);
      bh[f] = *(const short8*)(Bhs + (wc * 64 + f * 16 + lm) * 64 + g * 16);
      bl[f] = *(const short8*)(Bls + (wc * 64 + f * 16 + lm) * 64 + g * 16);
    }
#pragma unroll
    for (int fm = 0; fm < 4; ++fm)
#pragma unroll
      for (int fn = 0; fn < 4; ++fn) {
        acc[fm][fn] = mfma16(ah[fm], bh[fn], acc[fm][fn]);
        acc[fm][fn] = mfma16(ah[fm], bl[fn], acc[fm][fn]);
        acc[fm][fn] = mfma16(al[fm], bh[fn], acc[fm][fn]);
      }
  }

  // epilogue: +bias, store hi-only TILED [b][kt][feat][32]
#pragma unroll
  for (int fn = 0; fn < 4; ++fn) {
    const int n = n0 + wc * 64 + fn * 16 + lm;
    const float bv = bias[n];
#pragma unroll
    for (int fm = 0; fm < 4; ++fm) {
      const int mg = m0 + wr * 64 + fm * 16 + g * 4;
      const int bb = mg >> 10, node = mg & 1023;
      const int kt = node >> 5, ko = node & 31;
      ushort4 hh;
      uint16_t* hp = (uint16_t*)&hh;
#pragma unroll
      for (int e = 0; e < 4; ++e) hp[e] = f2bf(acc[fm][fn][e] + bv);
      const size_t o = ((size_t)(bb * 32 + kt) * 256 + n) * 32 + ko;
      *(ushort4*)(Yth + o) = hh;
    }
  }
}

// ---------------- aggregate: Z = An[b] @ Yh, mask, gelu ----------------
// BM=128, BN=128, BK=32. Grid 512 (2 blocks/CU). 4 waves (2M x 2N), wave
// tile 64x64 (acc[4][4]). 3-slot LDS ring, slot = [A 8KB | Yh-half 8KB].
// 4 GLD/wave/step (chunks c = w*4+j; c<8 -> A, else Y-half). vmcnt(4).
#define STAGE(T, SSL) {                                                        \
    _Pragma("unroll")                                                          \
    for (int j = 0; j < 4; ++j) {                                              \
      const int c = w * 4 + j;                                                 \
      const uint16_t* src = (c < 8)                                            \
          ? aStep + (size_t)(T) * 4096 + c * 512                               \
          : yStep + (size_t)(T) * 8192 + (c - 8) * 512;                        \
      GLD16(src, smem + (SSL) + c * 1024);                                     \
    }                                                                          \
  }

template <bool LAST>
__global__ __launch_bounds__(256, 2) void k_agg(
    const uint16_t* __restrict__ An,
    const uint16_t* __restrict__ Yth,
    const float* __restrict__ mask,
    uint16_t* __restrict__ Xh, uint16_t* __restrict__ Xl,
    float* __restrict__ out) {
  __shared__ __align__(16) uint8_t smem[49152];   // 3 x 16384 ring
  const int tid = threadIdx.x;
  const int lane = tid & 63;
  const int w = tid >> 6;               // 0..3
  const int wm = w >> 1, wn = w & 1;    // 2(M) x 2(N)
  const int id = blockIdx.x;            // 0..511
  const int swz = (id & 7) * 64 + (id >> 3);      // XCD-chunked (bijective)
  const int b = swz >> 4;               // batch
  const int rest = swz & 15;
  const int mb = rest >> 1;             // 128-row block
  const int nh = rest & 1;              // feature half
  const int lm = lane & 15, g = lane >> 4;

  // per-lane staging sources (tiled layouts are GLD-linear)
  const uint16_t* aStep = An + (size_t)(b * 8 + mb) * 131072 + lane * 8;
  const uint16_t* yStep = Yth + (size_t)b * 262144 + nh * 4096 + lane * 8;

  // fragment read offsets (byte, slot-local)
  const int aoff = (wm * 64 + lm) * 64 + g * 16;           // + fm*1024
  const int boff = 8192 + (wn * 64 + lm) * 64 + g * 16;    // + fn*1024

  f32x4 acc[4][4] = {};

  // prologue: stage tiles 0,1 into slots 0,1
  STAGE(0, 0);
  STAGE(1, 16384);

  int csl = 0, ssl = 32768;   // compute-slot, stage-slot byte offsets
#pragma unroll 1
  for (int t = 0; t < 32; ++t) {
    if (t < 31) { asm volatile("s_waitcnt vmcnt(4)" ::: "memory"); }
    else        { asm volatile("s_waitcnt vmcnt(0)" ::: "memory"); }
    __builtin_amdgcn_s_barrier();
    __builtin_amdgcn_sched_barrier(0);
    if (t < 30) { STAGE(t + 2, ssl); }
    __builtin_amdgcn_sched_barrier(0);

    const uint8_t* sb = smem + csl;
    short8 af[4];
#pragma unroll
    for (int f = 0; f < 4; ++f) af[f] = *(const short8*)(sb + aoff + f * 1024);
    __builtin_amdgcn_s_setprio(1);
#pragma unroll
    for (int fn = 0; fn < 4; ++fn) {
      const short8 hf = *(const short8*)(sb + boff + fn * 1024);
#pragma unroll
      for (int fm = 0; fm < 4; ++fm)
        acc[fm][fn] = mfma16(af[fm], hf, acc[fm][fn]);
    }
    __builtin_amdgcn_s_setprio(0);

    csl += 16384; if (csl == 49152) csl = 0;
    ssl += 16384; if (ssl == 49152) ssl = 0;
  }

  // epilogue: mask (per out-node), exact gelu, store row-major
  const float* mk_b = mask + b * 1024;
#pragma unroll
  for (int fm = 0; fm < 4; ++fm) {
    const int m = mb * 128 + wm * 64 + fm * 16 + g * 4;
    float mk[4];
#pragma unroll
    for (int e = 0; e < 4; ++e) mk[e] = mk_b[m + e];
#pragma unroll
    for (int fn = 0; fn < 4; ++fn) {
      const int n = nh * 128 + wn * 64 + fn * 16 + lm;
#pragma unroll
      for (int e = 0; e < 4; ++e) {
        const float v = gelu_exact(acc[fm][fn][e] * mk[e]);
        const size_t o = ((size_t)(b * 1024 + m + e)) * 256 + n;
        if (LAST) {
          out[o] = v;
        } else {
          const uint16_t hb = f2bf(v);
          Xh[o] = hb;
          Xl[o] = f2bf(v - bf2f(hb));
        }
      }
    }
  }
}

extern "C" void kernel_launch(void* const* d_in, const int* in_sizes, int n_in,
                              void* d_out, int out_size, void* d_ws, size_t ws_size,
                              hipStream_t stream) {
  const float* x    = (const float*)d_in[0];
  const float* mask = (const float*)d_in[1];
  const float* adj  = (const float*)d_in[2];
  const float* W[3]  = {(const float*)d_in[3], (const float*)d_in[5], (const float*)d_in[7]};
  const float* bs[3] = {(const float*)d_in[4], (const float*)d_in[6], (const float*)d_in[8]};

  uint8_t* ws = (uint8_t*)d_ws;
  uint16_t* An  = (uint16_t*)(ws);                    // 67108864 B (tiled)
  uint16_t* Xh  = (uint16_t*)(ws + 67108864);         // 16777216
  uint16_t* Xl  = (uint16_t*)(ws + 83886080);         // 16777216
  uint16_t* Yth = (uint16_t*)(ws + 100663296);        // 16777216 (tiled)
  uint16_t* Wh  = (uint16_t*)(ws + 134217728);        // 393216
  uint16_t* Wl  = (uint16_t*)(ws + 134610944);        // 393216

  k_split<<<dim3(8192), 256, 0, stream>>>(x, Xh, Xl, 2097152);
  for (int i = 0; i < 3; ++i)
    k_split<<<dim3(64), 256, 0, stream>>>(W[i], Wh + i * 65536, Wl + i * 65536, 16384);
  k_norm_adj<<<dim3(32768), 256, 0, stream>>>(adj, An);

  for (int l = 0; l < 3; ++l) {
    k_linear<<<dim3(256, 2), 256, 0, stream>>>(Xh, Xl, Wh + l * 65536, Wl + l * 65536,
                                               bs[l], Yth);
    if (l < 2)
      k_agg<false><<<dim3(512), 256, 0, stream>>>(An, Yth, mask, Xh, Xl, nullptr);
    else
      k_agg<true><<<dim3(512), 256, 0, stream>>>(An, Yth, mask, nullptr, nullptr,
                                                 (float*)d_out);
  }
}

// Round 12
// 184.687 us; speedup vs baseline: 1.5239x; 1.0854x over previous
//
#include <hip/hip_runtime.h>
#include <stdint.h>

// GraphConvLayer: 3x { x = X@W^T + b; x = Ahat @ x; x *= mask; x = gelu(x) }
// B=32, N=1024, D=256.
// R12: bf16-only inter-layer activations (drop Xl; R8 evidence says rounding
//      terms below ~3e-5 don't move absmax). k_linear 2-term (Xh-Wh + Xh-Wl),
//      24 chunks/step. k_agg: 4-slot ring depth-3, counted vmcnt(8).
// Tiled layouts (bf16, 16B-aligned):
//   An : [b][mb=node/128][kt=k/32][row 128][32]   tile stride 4096 elems
//   Yt : [b][kt=node/32][feat 256][32]            tile stride 8192 elems

typedef __attribute__((ext_vector_type(8))) short short8;   // 8 bf16 (4 VGPRs)
typedef __attribute__((ext_vector_type(4))) float f32x4;    // MFMA acc

__device__ __forceinline__ uint16_t f2bf(float f) {
  uint32_t u = __float_as_uint(f);
  u += 0x7FFF + ((u >> 16) & 1);          // RNE
  return (uint16_t)(u >> 16);
}
__device__ __forceinline__ float bf2f(uint16_t h) {
  return __uint_as_float(((uint32_t)h) << 16);
}
__device__ __forceinline__ float gelu_exact(float v) {
  return 0.5f * v * (1.0f + erff(v * 0.70710678118654752f));
}
__device__ __forceinline__ f32x4 mfma16(short8 a, short8 b, f32x4 c) {
  return __builtin_amdgcn_mfma_f32_16x16x32_bf16(a, b, c, 0, 0, 0);
}

#define GLD16(gsrc, ldst) __builtin_amdgcn_global_load_lds(                    \
    (const __attribute__((address_space(1))) void*)(gsrc),                     \
    (__attribute__((address_space(3))) void*)(ldst), 16, 0, 0)

// ---------------- cast f32 -> bf16 (hi only) ----------------
__global__ void k_cast(const float* __restrict__ src, uint16_t* __restrict__ h,
                       int n4) {
  int i = blockIdx.x * blockDim.x + threadIdx.x;
  if (i >= n4) return;
  const float4 v = ((const float4*)src)[i];
  float vv[4] = {v.x, v.y, v.z, v.w};
  ushort4 hh;
  uint16_t* hp = (uint16_t*)&hh;
#pragma unroll
  for (int e = 0; e < 4; ++e) hp[e] = f2bf(vv[e]);
  ((ushort4*)h)[i] = hh;
}

// ---------------- split f32 -> bf16 hi/lo (weights only) ----------------
__global__ void k_split(const float* __restrict__ src, uint16_t* __restrict__ h,
                        uint16_t* __restrict__ l, int n4) {
  int i = blockIdx.x * blockDim.x + threadIdx.x;
  if (i >= n4) return;
  const float4 v = ((const float4*)src)[i];
  float vv[4] = {v.x, v.y, v.z, v.w};
  ushort4 hh, ll;
  uint16_t* hp = (uint16_t*)&hh;
  uint16_t* lp = (uint16_t*)&ll;
#pragma unroll
  for (int e = 0; e < 4; ++e) {
    uint16_t hb = f2bf(vv[e]);
    hp[e] = hb;
    lp[e] = f2bf(vv[e] - bf2f(hb));
  }
  ((ushort4*)h)[i] = hh;
  ((ushort4*)l)[i] = ll;
}

// ---------------- row-normalize adj -> bf16, TILED store ----------------
__global__ void k_norm_adj(const float* __restrict__ adj, uint16_t* __restrict__ An) {
  const int r = blockIdx.x;       // 0..32767 = b*1024 + node
  const int t = threadIdx.x;      // 0..255, handles k = t*4 .. t*4+3
  const float* row = adj + (size_t)r * 1024;
  const float4 v = *(const float4*)(row + t * 4);
  float s = v.x + v.y + v.z + v.w;
#pragma unroll
  for (int off = 32; off; off >>= 1) s += __shfl_down(s, off);
  __shared__ float ws[4];
  if ((t & 63) == 0) ws[t >> 6] = s;
  __syncthreads();
  const float deg = ws[0] + ws[1] + ws[2] + ws[3];
  const float dinv = (deg != 0.f) ? 1.f / deg : 0.f;
  ushort4 o;
  uint16_t* op = (uint16_t*)&o;
  float vv[4] = {v.x, v.y, v.z, v.w};
#pragma unroll
  for (int e = 0; e < 4; ++e) op[e] = f2bf(vv[e] * dinv);
  // tiled: [b][mb][kt][row 128][32]
  const int b = r >> 10, node = r & 1023;
  const int mb = node >> 7, rr = node & 127;
  const int kt = t >> 3, ko = (t * 4) & 31;
  const size_t oo = (size_t)(b * 8 + mb) * 131072 + kt * 4096 + rr * 32 + ko;
  *(ushort4*)(An + oo) = o;
}

// ---------------- linear: Yt = (Xh @ W^T + b), 2-term, TILED store ----------------
// per K-step: 24 chunks (Xh 8 | Wh 8 | Wl 8), 6 GLD/wave; 32 MFMA/wave.
__global__ __launch_bounds__(256) void k_linear(
    const uint16_t* __restrict__ Xh,
    const uint16_t* __restrict__ Wh, const uint16_t* __restrict__ Wl,
    const float* __restrict__ bias,
    uint16_t* __restrict__ Yth) {
  __shared__ __align__(16) uint8_t smem[24576];  // Xh|Wh|Wl tiles, 8KB each
  const int tid = threadIdx.x;
  const int lane = tid & 63;
  const int wave = tid >> 6;
  const int wr = wave >> 1, wc = wave & 1;
  const int m0 = blockIdx.x * 128;   // global row (b*1024+node)
  const int n0 = blockIdx.y * 128;   // out-feature
  const int lm = lane & 15, g = lane >> 4;
  const int srow = lane >> 2;
  const int skof = (lane & 3) * 8;

  f32x4 acc[4][4] = {};

  for (int kt = 0; kt < 8; ++kt) {
    const int k0 = kt * 32;
    __syncthreads();
#pragma unroll
    for (int j = 0; j < 6; ++j) {
      const int c = j * 4 + wave;    // 0..23
      const int sub = c & 7, which = c >> 3;
      const int row = sub * 16 + srow;
      const uint16_t* src;
      if (which == 0)      src = Xh + (size_t)(m0 + row) * 256 + k0 + skof;
      else if (which == 1) src = Wh + (size_t)(n0 + row) * 256 + k0 + skof;
      else                 src = Wl + (size_t)(n0 + row) * 256 + k0 + skof;
      GLD16(src, smem + c * 1024);
    }
    asm volatile("s_waitcnt vmcnt(0)" ::: "memory");
    __syncthreads();

    const uint8_t* Ahs = smem;
    const uint8_t* Bhs = smem + 8192;
    const uint8_t* Bls = smem + 16384;
    short8 ah[4], bh[4], bl[4];
#pragma unroll
    for (int f = 0; f < 4; ++f) {
      ah[f] = *(const short8*)(Ahs + (wr * 64 + f * 16 + lm) * 64 + g * 16);
      bh[f] = *(const short8*)(Bhs + (wc * 64 + f * 16 + lm) * 64 + g * 16);
      bl[f] = *(const short8*)(Bls + (wc * 64 + f * 16 + lm) * 64 + g * 16);
    }
#pragma unroll
    for (int fm = 0; fm < 4; ++fm)
#pragma unroll
      for (int fn = 0; fn < 4; ++fn) {
        acc[fm][fn] = mfma16(ah[fm], bh[fn], acc[fm][fn]);
        acc[fm][fn] = mfma16(ah[fm], bl[fn], acc[fm][fn]);
      }
  }

  // epilogue: +bias, store hi-only TILED [b][kt][feat][32]
#pragma unroll
  for (int fn = 0; fn < 4; ++fn) {
    const int n = n0 + wc * 64 + fn * 16 + lm;
    const float bv = bias[n];
#pragma unroll
    for (int fm = 0; fm < 4; ++fm) {
      const int mg = m0 + wr * 64 + fm * 16 + g * 4;
      const int bb = mg >> 10, node = mg & 1023;
      const int kt = node >> 5, ko = node & 31;
      ushort4 hh;
      uint16_t* hp = (uint16_t*)&hh;
#pragma unroll
      for (int e = 0; e < 4; ++e) hp[e] = f2bf(acc[fm][fn][e] + bv);
      const size_t o = ((size_t)(bb * 32 + kt) * 256 + n) * 32 + ko;
      *(ushort4*)(Yth + o) = hh;
    }
  }
}

// ---------------- aggregate: Z = An[b] @ Yh, mask, gelu ----------------
// BM=128, BN=128, BK=32. Grid 512 (2 blocks/CU). 4 waves (2M x 2N), wave
// tile 64x64 (acc[4][4]). 4-slot LDS ring (slot = A 8KB | Yh-half 8KB),
// depth-3 prefetch, counted vmcnt(8). 4 GLD/wave/step.
#define STAGE(T, SSL) {                                                        \
    _Pragma("unroll")                                                          \
    for (int j = 0; j < 4; ++j) {                                              \
      const int c = w * 4 + j;                                                 \
      const uint16_t* src = (c < 8)                                            \
          ? aStep + (size_t)(T) * 4096 + c * 512                               \
          : yStep + (size_t)(T) * 8192 + (c - 8) * 512;                        \
      GLD16(src, smem + (SSL) + c * 1024);                                     \
    }                                                                          \
  }

template <bool LAST>
__global__ __launch_bounds__(256, 2) void k_agg(
    const uint16_t* __restrict__ An,
    const uint16_t* __restrict__ Yth,
    const float* __restrict__ mask,
    uint16_t* __restrict__ Xh,
    float* __restrict__ out) {
  __shared__ __align__(16) uint8_t smem[65536];   // 4 x 16384 ring
  const int tid = threadIdx.x;
  const int lane = tid & 63;
  const int w = tid >> 6;               // 0..3
  const int wm = w >> 1, wn = w & 1;    // 2(M) x 2(N)
  const int id = blockIdx.x;            // 0..511
  const int swz = (id & 7) * 64 + (id >> 3);      // XCD-chunked (bijective)
  const int b = swz >> 4;               // batch
  const int rest = swz & 15;
  const int mb = rest >> 1;             // 128-row block
  const int nh = rest & 1;              // feature half
  const int lm = lane & 15, g = lane >> 4;

  // per-lane staging sources (tiled layouts are GLD-linear)
  const uint16_t* aStep = An + (size_t)(b * 8 + mb) * 131072 + lane * 8;
  const uint16_t* yStep = Yth + (size_t)b * 262144 + nh * 4096 + lane * 8;

  // fragment read offsets (byte, slot-local)
  const int aoff = (wm * 64 + lm) * 64 + g * 16;           // + fm*1024
  const int boff = 8192 + (wn * 64 + lm) * 64 + g * 16;    // + fn*1024

  f32x4 acc[4][4] = {};

  // prologue: stage tiles 0,1,2 into slots 0,1,2
  STAGE(0, 0);
  STAGE(1, 16384);
  STAGE(2, 32768);

  int csl = 0, ssl = 49152;   // compute-slot, stage-slot byte offsets
#pragma unroll 1
  for (int t = 0; t < 32; ++t) {
    if (t < 30)      { asm volatile("s_waitcnt vmcnt(8)" ::: "memory"); }
    else if (t == 30){ asm volatile("s_waitcnt vmcnt(4)" ::: "memory"); }
    else             { asm volatile("s_waitcnt vmcnt(0)" ::: "memory"); }
    __builtin_amdgcn_s_barrier();
    __builtin_amdgcn_sched_barrier(0);
    if (t < 29) { STAGE(t + 3, ssl); }
    __builtin_amdgcn_sched_barrier(0);

    const uint8_t* sb = smem + csl;
    short8 af[4];
#pragma unroll
    for (int f = 0; f < 4; ++f) af[f] = *(const short8*)(sb + aoff + f * 1024);
    __builtin_amdgcn_s_setprio(1);
#pragma unroll
    for (int fn = 0; fn < 4; ++fn) {
      const short8 hf = *(const short8*)(sb + boff + fn * 1024);
#pragma unroll
      for (int fm = 0; fm < 4; ++fm)
        acc[fm][fn] = mfma16(af[fm], hf, acc[fm][fn]);
    }
    __builtin_amdgcn_s_setprio(0);

    csl += 16384; if (csl == 65536) csl = 0;
    ssl += 16384; if (ssl == 65536) ssl = 0;
  }

  // epilogue: mask (per out-node), exact gelu, store row-major (bf16 hi only)
  const float* mk_b = mask + b * 1024;
#pragma unroll
  for (int fm = 0; fm < 4; ++fm) {
    const int m = mb * 128 + wm * 64 + fm * 16 + g * 4;
    float mk[4];
#pragma unroll
    for (int e = 0; e < 4; ++e) mk[e] = mk_b[m + e];
#pragma unroll
    for (int fn = 0; fn < 4; ++fn) {
      const int n = nh * 128 + wn * 64 + fn * 16 + lm;
#pragma unroll
      for (int e = 0; e < 4; ++e) {
        const float v = gelu_exact(acc[fm][fn][e] * mk[e]);
        const size_t o = ((size_t)(b * 1024 + m + e)) * 256 + n;
        if (LAST) {
          out[o] = v;
        } else {
          Xh[o] = f2bf(v);
        }
      }
    }
  }
}

extern "C" void kernel_launch(void* const* d_in, const int* in_sizes, int n_in,
                              void* d_out, int out_size, void* d_ws, size_t ws_size,
                              hipStream_t stream) {
  const float* x    = (const float*)d_in[0];
  const float* mask = (const float*)d_in[1];
  const float* adj  = (const float*)d_in[2];
  const float* W[3]  = {(const float*)d_in[3], (const float*)d_in[5], (const float*)d_in[7]};
  const float* bs[3] = {(const float*)d_in[4], (const float*)d_in[6], (const float*)d_in[8]};

  uint8_t* ws = (uint8_t*)d_ws;
  uint16_t* An  = (uint16_t*)(ws);                    // 67108864 B (tiled)
  uint16_t* Xh  = (uint16_t*)(ws + 67108864);         // 16777216
  uint16_t* Yth = (uint16_t*)(ws + 83886080);         // 16777216 (tiled)
  uint16_t* Wh  = (uint16_t*)(ws + 100663296);        // 393216
  uint16_t* Wl  = (uint16_t*)(ws + 101056512);        // 393216

  k_cast<<<dim3(8192), 256, 0, stream>>>(x, Xh, 2097152);
  for (int i = 0; i < 3; ++i)
    k_split<<<dim3(64), 256, 0, stream>>>(W[i], Wh + i * 65536, Wl + i * 65536, 16384);
  k_norm_adj<<<dim3(32768), 256, 0, stream>>>(adj, An);

  for (int l = 0; l < 3; ++l) {
    k_linear<<<dim3(256, 2), 256, 0, stream>>>(Xh, Wh + l * 65536, Wl + l * 65536,
                                               bs[l], Yth);
    if (l < 2)
      k_agg<false><<<dim3(512), 256, 0, stream>>>(An, Yth, mask, Xh, nullptr);
    else
      k_agg<true><<<dim3(512), 256, 0, stream>>>(An, Yth, mask, nullptr,
                                                 (float*)d_out);
  }
}